// Round 3
// baseline (566.405 us; speedup 1.0000x reference)
//
#include <hip/hip_runtime.h>

typedef unsigned short u16;
typedef unsigned int u32;

#define T_LEN 8192
#define MD    2048
#define NH    64
#define NCH   64
#define LCH   128   // T_LEN / NCH

typedef __attribute__((ext_vector_type(8))) short bf16x8;
typedef __attribute__((ext_vector_type(4))) float f32x4;

__device__ __forceinline__ u16 f2bf(float f){
  u32 u = __float_as_uint(f);
  u += 0x7fffu + ((u >> 16) & 1u);
  return (u16)(u >> 16);
}

// ---------------- setup: gamma, xi ----------------
__global__ __launch_bounds__(256) void k_prep(const float* __restrict__ B,
                                              const float* __restrict__ gamma_log,
                                              float* __restrict__ gam,
                                              float* __restrict__ xi)
{
  const int h = blockIdx.x, tid = threadIdx.x;
  const float* Bh = B + (size_t)h * (32 * MD);
  float s = 0.f;
  for (int i = tid; i < 32 * MD; i += 256){ float v = Bh[i]; s = fmaf(v, v, s); }
  for (int o = 32; o; o >>= 1) s += __shfl_down(s, o);
  __shared__ float red[4];
  if ((tid & 63) == 0) red[tid >> 6] = s;
  __syncthreads();
  if (tid == 0){
    float t = red[0] + red[1] + red[2] + red[3];
    float g = expf(-expf(gamma_log[h]));
    gam[h] = g;
    xi[h] = sqrtf((1.f - g * g) / t);
  }
}

// ---------------- P = expm(M - M^T), one 32x32 block per head ----------------
__global__ __launch_bounds__(1024) void k_expm(const float* __restrict__ Mp,
                                               float* __restrict__ P)
{
  const int h = blockIdx.x;
  const int j = threadIdx.x, i = threadIdx.y;
  const int tid = i * 32 + j;
  __shared__ float X[32][32], Tm[32][32], S[32][32];
  __shared__ float red[16];
  __shared__ float s_fn2;
  const float* Mh = Mp + (size_t)h * 1024;
  float a = Mh[i * 32 + j] - Mh[j * 32 + i];
  float v = a * a;
  for (int o = 32; o; o >>= 1) v += __shfl_down(v, o);
  if ((tid & 63) == 0) red[tid >> 6] = v;
  __syncthreads();
  if (tid == 0){
    float t = 0.f;
    for (int q = 0; q < 16; ++q) t += red[q];
    s_fn2 = t;
  }
  __syncthreads();
  const float fn = sqrtf(s_fn2);
  int sc = 0; float t = fn;
  while (t > 0.25f && sc < 24){ t *= 0.5f; ++sc; }
  const float scale = exp2f((float)(-sc));
  X[i][j] = a * scale;
  Tm[i][j] = a * scale;
  S[i][j] = a * scale + (i == j ? 1.f : 0.f);
  __syncthreads();
  // Taylor: S = I + X + X^2/2! + ... up to k=13  (||X||_F <= 0.25)
  for (int k = 2; k <= 13; ++k){
    float acc = 0.f;
    #pragma unroll
    for (int m = 0; m < 32; ++m) acc = fmaf(Tm[i][m], X[m][j], acc);
    acc *= (1.f / (float)k);
    __syncthreads();
    Tm[i][j] = acc;
    S[i][j] += acc;
    __syncthreads();
  }
  // squaring
  for (int q = 0; q < sc; ++q){
    float acc = 0.f;
    #pragma unroll
    for (int m = 0; m < 32; ++m) acc = fmaf(S[i][m], S[m][j], acc);
    __syncthreads();
    S[i][j] = acc;
    __syncthreads();
  }
  P[(size_t)h * 1024 + i * 32 + j] = S[i][j];
}

// ---------------- BP[h*32+n][i] = xi_h * sum_m P[h][m][n] * B[h][m][i] (bf16) ----------------
__global__ __launch_bounds__(256) void k_bp(const float* __restrict__ B,
                                            const float* __restrict__ P,
                                            const float* __restrict__ xi,
                                            u16* __restrict__ BP)
{
  const int h = blockIdx.y;
  const int i = blockIdx.x * 256 + threadIdx.x;
  __shared__ float Pl[32][32];
  for (int q = threadIdx.x; q < 1024; q += 256) ((float*)Pl)[q] = P[(size_t)h*1024 + q];
  __syncthreads();
  const float x = xi[h];
  float breg[32];
  #pragma unroll
  for (int m = 0; m < 32; ++m) breg[m] = B[(size_t)h*32*MD + (size_t)m*MD + i];
  for (int n = 0; n < 32; ++n){
    float acc = 0.f;
    #pragma unroll
    for (int m = 0; m < 32; ++m) acc = fmaf(Pl[m][n], breg[m], acc);
    BP[(size_t)(h*32 + n)*MD + i] = f2bf(x * acc);
  }
}

// ---------------- CP[m][h*32+i] = sum_n C[m][h*32+n] * P[h][n][i] (bf16) ----------------
__global__ __launch_bounds__(256) void k_cp(const float* __restrict__ C,
                                            const float* __restrict__ P,
                                            u16* __restrict__ CP)
{
  const int h = blockIdx.y;
  const int m0 = blockIdx.x * 64;
  __shared__ float Pl[32][32];
  for (int q = threadIdx.x; q < 1024; q += 256) ((float*)Pl)[q] = P[(size_t)h*1024 + q];
  __syncthreads();
  const int ml = threadIdx.x >> 5, ii = threadIdx.x & 31;
  for (int sub = 0; sub < 8; ++sub){
    const int m = m0 + sub*8 + ml;
    const float* Cm = C + (size_t)m*MD + h*32;
    float acc = 0.f;
    #pragma unroll
    for (int n = 0; n < 32; ++n) acc = fmaf(Cm[n], Pl[n][ii], acc);
    CP[(size_t)m*MD + h*32 + ii] = f2bf(acc);
  }
}

// ---------------- f32 -> bf16 convert ----------------
__global__ __launch_bounds__(256) void k_cvt(const float* __restrict__ in, u16* __restrict__ out, int n4)
{
  const int idx = blockIdx.x * 256 + threadIdx.x;
  const int stride = gridDim.x * 256;
  for (int i = idx; i < n4; i += stride){
    float4 v = ((const float4*)in)[i];
    ushort4 o;
    o.x = f2bf(v.x); o.y = f2bf(v.y); o.z = f2bf(v.z); o.w = f2bf(v.w);
    ((ushort4*)out)[i] = o;
  }
}

// ---------------- bf16 GEMM: out[M,N] = A[M,K] * W[N,K]^T  (m97 structure) ----------------
// FUSE==0: out -> bf16 (outb);  FUSE==1: out -> f32 (outf) + D[col]*U[row,col]
template<int FUSE>
__global__ __launch_bounds__(256) void gemm_bt(
    const u16* __restrict__ A, const u16* __restrict__ W,
    u16* __restrict__ outb, float* __restrict__ outf,
    const float* __restrict__ Dv, const float* __restrict__ U,
    int M, int N, int K)
{
  __shared__ u16 sA[128*32];
  __shared__ u16 sB[128*32];
  const int tid = threadIdx.x;
  const int lane = tid & 63;
  const int wv = tid >> 6;            // wave 0..3
  const int wm = wv >> 1, wn = wv & 1;
  const int lr = lane & 15, lk = lane >> 4;
  const int bm = blockIdx.y, bn = blockIdx.x;

  f32x4 acc[4][4] = {};

  // staging: flat16 = issue*256 + tid; row = flat16/4; ks = flat16%4.
  // LDS content at (row, slot s) holds global k-slot (s + rot(row))&3, rot(row)=(row>>1)&3.
  int g_off[2];
  #pragma unroll
  for (int i = 0; i < 2; ++i){
    const int flat = i*256 + tid;
    const int row = flat >> 2, ks = flat & 3;
    const int rot = (row >> 1) & 3;
    const int gs = (ks + rot) & 3;
    g_off[i] = row * K + gs * 8;
  }
  const u16* Abase = A + (size_t)bm * 128 * K;
  const u16* Wbase = W + (size_t)bn * 128 * K;

  // fragment read offsets (u16 units): want global slot lk -> LDS slot (lk - rot)&3
  int a_rd[4], b_rd[4];
  #pragma unroll
  for (int mi = 0; mi < 4; ++mi){
    const int row = wm*64 + mi*16 + lr;
    const int slot = (lk - ((row >> 1) & 3)) & 3;
    a_rd[mi] = row*32 + slot*8;
  }
  #pragma unroll
  for (int ni = 0; ni < 4; ++ni){
    const int row = wn*64 + ni*16 + lr;
    const int slot = (lk - ((row >> 1) & 3)) & 3;
    b_rd[ni] = row*32 + slot*8;
  }

  for (int kt = 0; kt < K; kt += 32){
    #pragma unroll
    for (int i = 0; i < 2; ++i){
      __builtin_amdgcn_global_load_lds(
        (const __attribute__((address_space(1))) void*)(Abase + g_off[i] + kt),
        (__attribute__((address_space(3))) void*)(sA + (i*256 + wv*64)*8), 16, 0, 0);
      __builtin_amdgcn_global_load_lds(
        (const __attribute__((address_space(1))) void*)(Wbase + g_off[i] + kt),
        (__attribute__((address_space(3))) void*)(sB + (i*256 + wv*64)*8), 16, 0, 0);
    }
    __syncthreads();
    bf16x8 af[4], bfr[4];
    #pragma unroll
    for (int mi = 0; mi < 4; ++mi) af[mi] = *(const bf16x8*)(sA + a_rd[mi]);
    #pragma unroll
    for (int ni = 0; ni < 4; ++ni) bfr[ni] = *(const bf16x8*)(sB + b_rd[ni]);
    #pragma unroll
    for (int mi = 0; mi < 4; ++mi)
      #pragma unroll
      for (int ni = 0; ni < 4; ++ni)
        acc[mi][ni] = __builtin_amdgcn_mfma_f32_16x16x32_bf16(af[mi], bfr[ni], acc[mi][ni], 0, 0, 0);
    __syncthreads();
  }

  // epilogue: D row = lk*4 + r, col = lr (within each 16x16 fragment)
  #pragma unroll
  for (int mi = 0; mi < 4; ++mi){
    #pragma unroll
    for (int ni = 0; ni < 4; ++ni){
      #pragma unroll
      for (int r = 0; r < 4; ++r){
        const int row = bm*128 + wm*64 + mi*16 + lk*4 + r;
        const int col = bn*128 + wn*64 + ni*16 + lr;
        if (FUSE == 0){
          outb[(size_t)row*N + col] = f2bf(acc[mi][ni][r]);
        } else {
          outf[(size_t)row*N + col] = acc[mi][ni][r] + Dv[col]*U[(size_t)row*N + col];
        }
      }
    }
  }
}

// ---------------- scan phase 1: chunk-local end states ----------------
// layout: lane l handles head g*4 + (l>>4), pair p = l&15 (elements 2p, 2p+1)
__global__ __launch_bounds__(64) void scan_p1(const u16* __restrict__ xbf, float* __restrict__ E,
                                              const float* __restrict__ gam, const float* __restrict__ th)
{
  const int g = blockIdx.x, c = blockIdx.y, l = threadIdx.x;
  const int head = g*4 + (l >> 4), p = l & 15;
  const float gamma = gam[head];
  const float theta = th[head*16 + p];
  const float cs = cosf(theta), sn = sinf(theta);
  float he = 0.f, ho = 0.f;
  const int off = g*128 + (l >> 4)*32 + p*2;
  const u16* px = xbf + (size_t)c*LCH*MD + off;
  #pragma unroll 4
  for (int t = 0; t < LCH; ++t){
    const u32 w = *(const u32*)px;
    const float xe = __uint_as_float(w << 16);
    const float xo = __uint_as_float(w & 0xffff0000u);
    const float te = fmaf(cs, he, -sn*ho);
    const float to = fmaf(sn, he,  cs*ho);
    he = fmaf(gamma, te, xe);
    ho = fmaf(gamma, to, xo);
    px += MD;
  }
  *(float2*)(E + (size_t)c*MD + off) = make_float2(he, ho);
}

// ---------------- scan phase 2: per-head combine over chunks; E[c] <- exclusive carry ----------------
__global__ __launch_bounds__(64) void scan_p2(float* __restrict__ E,
                                              const float* __restrict__ gam, const float* __restrict__ th)
{
  const int g = blockIdx.x, l = threadIdx.x;
  const int head = g*4 + (l >> 4), p = l & 15;
  const float gamma = gam[head];
  const float theta = th[head*16 + p];
  const float gL = expf((float)LCH * logf(gamma));
  const float aL = (float)LCH * theta;
  const float cL = cosf(aL), sL = sinf(aL);
  float ce = 0.f, co = 0.f;
  const int off = g*128 + (l >> 4)*32 + p*2;
  for (int c = 0; c < NCH; ++c){
    float2* Ep = (float2*)(E + (size_t)c*MD + off);
    const float2 e = *Ep;
    *Ep = make_float2(ce, co);
    const float te = gL * (cL*ce - sL*co);
    const float to = gL * (sL*ce + cL*co);
    ce = te + e.x;
    co = to + e.y;
  }
}

// ---------------- scan phase 3: replay chunks from carry, write hidden (bf16) ----------------
__global__ __launch_bounds__(64) void scan_p3(const u16* __restrict__ xbf, const float* __restrict__ E,
                                              u16* __restrict__ hid,
                                              const float* __restrict__ gam, const float* __restrict__ th)
{
  const int g = blockIdx.x, c = blockIdx.y, l = threadIdx.x;
  const int head = g*4 + (l >> 4), p = l & 15;
  const float gamma = gam[head];
  const float theta = th[head*16 + p];
  const float cs = cosf(theta), sn = sinf(theta);
  const int off = g*128 + (l >> 4)*32 + p*2;
  const float2 cr = *(const float2*)(E + (size_t)c*MD + off);
  float he = cr.x, ho = cr.y;
  const u16* px = xbf + (size_t)c*LCH*MD + off;
  u16* ph = hid + (size_t)c*LCH*MD + off;
  #pragma unroll 4
  for (int t = 0; t < LCH; ++t){
    const u32 w = *(const u32*)px;
    const float xe = __uint_as_float(w << 16);
    const float xo = __uint_as_float(w & 0xffff0000u);
    const float te = fmaf(cs, he, -sn*ho);
    const float to = fmaf(sn, he,  cs*ho);
    he = fmaf(gamma, te, xe);
    ho = fmaf(gamma, to, xo);
    *(u32*)ph = (u32)f2bf(he) | ((u32)f2bf(ho) << 16);
    px += MD;
    ph += MD;
  }
}

extern "C" void kernel_launch(void* const* d_in, const int* in_sizes, int n_in,
                              void* d_out, int out_size, void* d_ws, size_t ws_size,
                              hipStream_t stream) {
  const float* U  = (const float*)d_in[0];   // (T, MD)
  const float* TH = (const float*)d_in[1];   // (H, 16)
  const float* Mm = (const float*)d_in[2];   // (H, 32, 32)
  const float* B  = (const float*)d_in[3];   // (H, 32, MD)
  const float* C  = (const float*)d_in[4];   // (MD, MD)
  const float* Dv = (const float*)d_in[5];   // (MD,)
  const float* GL = (const float*)d_in[6];   // (H, 1)
  float* Y = (float*)d_out;

  char* w = (char*)d_ws;
  u16*   u_bf = (u16*)(w);                       // 32 MB
  u16*   x_bf = (u16*)(w + 33554432);            // 32 MB
  u16*   BPw  = (u16*)(w + 67108864);            // 8 MB
  u16*   CPw  = (u16*)(w + 75497472);            // 8 MB
  float* Pw   = (float*)(w + 83886080);          // 256 KB
  float* Ew   = (float*)(w + 84148224);          // 512 KB
  float* gam  = (float*)(w + 84672512);
  float* xiw  = (float*)(w + 84672768);
  u16*   hid  = u_bf;                            // alias: u_bf dead after GEMM1

  k_prep<<<NH, 256, 0, stream>>>(B, GL, gam, xiw);
  k_expm<<<NH, dim3(32, 32), 0, stream>>>(Mm, Pw);
  k_bp<<<dim3(8, NH), 256, 0, stream>>>(B, Pw, xiw, BPw);
  k_cp<<<dim3(32, NH), 256, 0, stream>>>(C, Pw, CPw);
  k_cvt<<<4096, 256, 0, stream>>>(U, u_bf, (T_LEN*MD)/4);

  gemm_bt<0><<<dim3(MD/128, T_LEN/128), 256, 0, stream>>>(
      u_bf, BPw, x_bf, nullptr, nullptr, nullptr, T_LEN, MD, MD);

  scan_p1<<<dim3(16, NCH), 64, 0, stream>>>(x_bf, Ew, gam, TH);
  scan_p2<<<16, 64, 0, stream>>>(Ew, gam, TH);
  scan_p3<<<dim3(16, NCH), 64, 0, stream>>>(x_bf, Ew, hid, gam, TH);

  gemm_bt<1><<<dim3(MD/128, T_LEN/128), 256, 0, stream>>>(
      hid, CPw, nullptr, Y, Dv, U, T_LEN, MD, MD);
}

// Round 4
// 482.837 us; speedup vs baseline: 1.1731x; 1.1731x over previous
//
#include <hip/hip_runtime.h>

typedef unsigned short u16;
typedef unsigned int u32;

#define T_LEN 8192
#define MD    2048
#define NH    64
#define NCH   64
#define LCH   128   // T_LEN / NCH

typedef __attribute__((ext_vector_type(8))) short bf16x8;
typedef __attribute__((ext_vector_type(4))) float f32x4;

__device__ __forceinline__ u16 f2bf(float f){
  u32 u = __float_as_uint(f);
  u += 0x7fffu + ((u >> 16) & 1u);
  return (u16)(u >> 16);
}

// ---------------- setup: gamma, xi ----------------
__global__ __launch_bounds__(256) void k_prep(const float* __restrict__ B,
                                              const float* __restrict__ gamma_log,
                                              float* __restrict__ gam,
                                              float* __restrict__ xi)
{
  const int h = blockIdx.x, tid = threadIdx.x;
  const float* Bh = B + (size_t)h * (32 * MD);
  float s = 0.f;
  for (int i = tid; i < 32 * MD; i += 256){ float v = Bh[i]; s = fmaf(v, v, s); }
  for (int o = 32; o; o >>= 1) s += __shfl_down(s, o);
  __shared__ float red[4];
  if ((tid & 63) == 0) red[tid >> 6] = s;
  __syncthreads();
  if (tid == 0){
    float t = red[0] + red[1] + red[2] + red[3];
    float g = expf(-expf(gamma_log[h]));
    gam[h] = g;
    xi[h] = sqrtf((1.f - g * g) / t);
  }
}

// ---------------- P = expm(M - M^T), one 32x32 block per head ----------------
__global__ __launch_bounds__(1024) void k_expm(const float* __restrict__ Mp,
                                               float* __restrict__ P)
{
  const int h = blockIdx.x;
  const int j = threadIdx.x, i = threadIdx.y;
  const int tid = i * 32 + j;
  __shared__ float X[32][32], Tm[32][32], S[32][32];
  __shared__ float red[16];
  __shared__ float s_fn2;
  const float* Mh = Mp + (size_t)h * 1024;
  float a = Mh[i * 32 + j] - Mh[j * 32 + i];
  float v = a * a;
  for (int o = 32; o; o >>= 1) v += __shfl_down(v, o);
  if ((tid & 63) == 0) red[tid >> 6] = v;
  __syncthreads();
  if (tid == 0){
    float t = 0.f;
    for (int q = 0; q < 16; ++q) t += red[q];
    s_fn2 = t;
  }
  __syncthreads();
  const float fn = sqrtf(s_fn2);
  int sc = 0; float t = fn;
  while (t > 0.25f && sc < 24){ t *= 0.5f; ++sc; }
  const float scale = exp2f((float)(-sc));
  X[i][j] = a * scale;
  Tm[i][j] = a * scale;
  S[i][j] = a * scale + (i == j ? 1.f : 0.f);
  __syncthreads();
  for (int k = 2; k <= 13; ++k){
    float acc = 0.f;
    #pragma unroll
    for (int m = 0; m < 32; ++m) acc = fmaf(Tm[i][m], X[m][j], acc);
    acc *= (1.f / (float)k);
    __syncthreads();
    Tm[i][j] = acc;
    S[i][j] += acc;
    __syncthreads();
  }
  for (int q = 0; q < sc; ++q){
    float acc = 0.f;
    #pragma unroll
    for (int m = 0; m < 32; ++m) acc = fmaf(S[i][m], S[m][j], acc);
    __syncthreads();
    S[i][j] = acc;
    __syncthreads();
  }
  P[(size_t)h * 1024 + i * 32 + j] = S[i][j];
}

// ---------------- BP[h*32+n][i] = xi_h * sum_m P[h][m][n] * B[h][m][i] (bf16) ----------------
__global__ __launch_bounds__(256) void k_bp(const float* __restrict__ B,
                                            const float* __restrict__ P,
                                            const float* __restrict__ xi,
                                            u16* __restrict__ BP)
{
  const int h = blockIdx.y;
  const int i = blockIdx.x * 256 + threadIdx.x;
  __shared__ float Pl[32][32];
  for (int q = threadIdx.x; q < 1024; q += 256) ((float*)Pl)[q] = P[(size_t)h*1024 + q];
  __syncthreads();
  const float x = xi[h];
  float breg[32];
  #pragma unroll
  for (int m = 0; m < 32; ++m) breg[m] = B[(size_t)h*32*MD + (size_t)m*MD + i];
  for (int n = 0; n < 32; ++n){
    float acc = 0.f;
    #pragma unroll
    for (int m = 0; m < 32; ++m) acc = fmaf(Pl[m][n], breg[m], acc);
    BP[(size_t)(h*32 + n)*MD + i] = f2bf(x * acc);
  }
}

// ---------------- CP[m][h*32+i] = sum_n C[m][h*32+n] * P[h][n][i] (bf16) ----------------
__global__ __launch_bounds__(256) void k_cp(const float* __restrict__ C,
                                            const float* __restrict__ P,
                                            u16* __restrict__ CP)
{
  const int h = blockIdx.y;
  const int m0 = blockIdx.x * 64;
  __shared__ float Pl[32][32];
  for (int q = threadIdx.x; q < 1024; q += 256) ((float*)Pl)[q] = P[(size_t)h*1024 + q];
  __syncthreads();
  const int ml = threadIdx.x >> 5, ii = threadIdx.x & 31;
  for (int sub = 0; sub < 8; ++sub){
    const int m = m0 + sub*8 + ml;
    const float* Cm = C + (size_t)m*MD + h*32;
    float acc = 0.f;
    #pragma unroll
    for (int n = 0; n < 32; ++n) acc = fmaf(Cm[n], Pl[n][ii], acc);
    CP[(size_t)m*MD + h*32 + ii] = f2bf(acc);
  }
}

// ---------------- f32 -> bf16 convert ----------------
__global__ __launch_bounds__(256) void k_cvt(const float* __restrict__ in, u16* __restrict__ out, int n4)
{
  const int idx = blockIdx.x * 256 + threadIdx.x;
  const int stride = gridDim.x * 256;
  for (int i = idx; i < n4; i += stride){
    float4 v = ((const float4*)in)[i];
    ushort4 o;
    o.x = f2bf(v.x); o.y = f2bf(v.y); o.z = f2bf(v.z); o.w = f2bf(v.w);
    ((ushort4*)out)[i] = o;
  }
}

// ================= 256x256 8-phase bf16 GEMM: out[M,N] = A[M,K] * W[N,K]^T =================
// M=8192, N=2048, K=2048. 512 threads = 8 waves (2M x 4N). BK=64, double-buffered LDS 128KiB.
// Swizzle: row r, 16B slot s -> LDS slot s ^ (r&7); applied on pre-swizzled global source
// (gload_lds dest stays lane-linear) and on ds_read addresses (same involution).
// Schedule: per tile 4 phases (quadrants A0B0, A0B1, A1B1, A1B0; B0 held in regs).
// Stage order lead-7-halves: P0(t)->A1(t+1), P1->A0(t+2), P2->B0(t+2), P3->B1(t+2).
// vmcnt(6) once per tile at P3 (3 halves in flight); vmcnt(0) at t==NT-2 (tail drain).
#define GBAR() __builtin_amdgcn_s_barrier()
#define GSB()  __builtin_amdgcn_sched_barrier(0)
#define GLGKM0() asm volatile("s_waitcnt lgkmcnt(0)" ::: "memory")

template<int FUSE>
__global__ __launch_bounds__(512, 1) void gemm256(
    const u16* __restrict__ A, const u16* __restrict__ W,
    u16* __restrict__ outb, float* __restrict__ outf,
    const float* __restrict__ Dv, const float* __restrict__ U)
{
  constexpr int K = 2048, NOUT = 2048, NT = K / 64;
  __shared__ u16 sm[65536];                 // 128 KiB: [buf0: A 16K u16, B 16K][buf1: A, B]
  const int tid = threadIdx.x;
  const int lane = tid & 63;
  const int wv = tid >> 6;
  const int wm = wv >> 2, wn = wv & 3;      // 2 x 4 waves, per-wave out 128x64
  const int lr = lane & 15, lk = lane >> 4;

  // T1: bijective XCD swizzle (nwg=256, 8 XCDs, 32 blocks each -> 4 bm-rows x 8 bn)
  const int bid = blockIdx.y * gridDim.x + blockIdx.x;
  const int swz = (bid & 7) * 32 + (bid >> 3);
  const int bn = swz & 7, bm = swz >> 3;

  const u16* Ablk = A + (size_t)bm * 256 * K;
  const u16* Wblk = W + (size_t)bn * 256 * K;

  // staging per-thread: row r0 = tid>>3 within issue, slot (tid&7) pre-swizzled by r&7
  const int r0 = tid >> 3;
  const size_t gthr = (size_t)r0 * K + (size_t)(((tid & 7) ^ (r0 & 7)) << 3);

  // fragment-read swizzled slot offsets (u16 units), slot = (ks*4+lk) ^ (lr&7)
  const int sl0 = ((lk ^ (lr & 7)) << 3);
  const int sl1 = (((4 + lk) ^ (lr & 7)) << 3);

  f32x4 acc[8][4] = {};
  bf16x8 a[4][2], b0[2][2], b1[2][2];

  // half types: 0=A0(rows0-127), 1=B0, 2=B1(rows128-255), 3=A1
#define STAGE(tt, y) do { \
    const int p_ = (tt) & 1; \
    const int rb_ = ((y) >= 2) ? 128 : 0; \
    const bool isA_ = ((y) == 0) || ((y) == 3); \
    const u16* gb_ = isA_ ? Ablk : Wblk; \
    u16* lb_ = sm + p_*32768 + (isA_ ? 0 : 16384); \
    _Pragma("unroll") for (int i_ = 0; i_ < 2; ++i_){ \
      const u16* g_ = gb_ + gthr + (size_t)(rb_ + i_*64) * K + (size_t)(tt) * 64; \
      u16* l_ = lb_ + (rb_ + i_*64 + wv*8) * 64; \
      __builtin_amdgcn_global_load_lds( \
        (const __attribute__((address_space(1))) void*)g_, \
        (__attribute__((address_space(3))) void*)l_, 16, 0, 0); \
    } \
  } while(0)

#define RD_A(qm) do { \
    const u16* sa_ = sm + p*32768 + ((qm)*128 + wm*64 + lr) * 64; \
    _Pragma("unroll") for (int mi_ = 0; mi_ < 4; ++mi_){ \
      a[mi_][0] = *(const bf16x8*)(sa_ + mi_*1024 + sl0); \
      a[mi_][1] = *(const bf16x8*)(sa_ + mi_*1024 + sl1); } \
  } while(0)

#define RD_B(qn, breg) do { \
    const u16* sb_ = sm + p*32768 + 16384 + ((qn)*128 + wn*32 + lr) * 64; \
    _Pragma("unroll") for (int ni_ = 0; ni_ < 2; ++ni_){ \
      breg[ni_][0] = *(const bf16x8*)(sb_ + ni_*1024 + sl0); \
      breg[ni_][1] = *(const bf16x8*)(sb_ + ni_*1024 + sl1); } \
  } while(0)

#define MM(mo, no, breg) do { \
    _Pragma("unroll") for (int mi_ = 0; mi_ < 4; ++mi_) \
    _Pragma("unroll") for (int ni_ = 0; ni_ < 2; ++ni_){ \
      acc[(mo)+mi_][(no)+ni_] = __builtin_amdgcn_mfma_f32_16x16x32_bf16(a[mi_][0], breg[ni_][0], acc[(mo)+mi_][(no)+ni_], 0, 0, 0); \
      acc[(mo)+mi_][(no)+ni_] = __builtin_amdgcn_mfma_f32_16x16x32_bf16(a[mi_][1], breg[ni_][1], acc[(mo)+mi_][(no)+ni_], 0, 0, 0); } \
  } while(0)

  // prologue: halves 0..6 = tile0 {A0,B0,B1,A1} + tile1 {A0,B0,B1}
  STAGE(0, 0); STAGE(0, 1); STAGE(0, 2); STAGE(0, 3);
  STAGE(1, 0); STAGE(1, 1); STAGE(1, 2);
  asm volatile("s_waitcnt vmcnt(6)" ::: "memory");   // tile 0 fully landed
  GSB(); GBAR();

  for (int t = 0; t < NT; ++t){
    const int p = t & 1;
    // ---- P0: quadrant (A0, B0) ----
    RD_A(0); RD_B(0, b0);
    if (t + 1 < NT) STAGE(t + 1, 3);
    GSB(); GBAR(); GLGKM0(); GSB();
    __builtin_amdgcn_s_setprio(1); MM(0, 0, b0); __builtin_amdgcn_s_setprio(0);
    GSB(); GBAR();
    // ---- P1: quadrant (A0, B1) ----
    RD_B(1, b1);
    if (t + 2 < NT) STAGE(t + 2, 0);
    GSB(); GBAR(); GLGKM0(); GSB();
    __builtin_amdgcn_s_setprio(1); MM(0, 2, b1); __builtin_amdgcn_s_setprio(0);
    GSB(); GBAR();
    // ---- P2: quadrant (A1, B1) ----
    RD_A(1);
    if (t + 2 < NT) STAGE(t + 2, 1);
    GSB(); GBAR(); GLGKM0(); GSB();
    __builtin_amdgcn_s_setprio(1); MM(4, 2, b1); __builtin_amdgcn_s_setprio(0);
    GSB(); GBAR();
    // ---- P3: quadrant (A1, B0) — no ds_read (b0 held in regs) ----
    if (t + 2 < NT) STAGE(t + 2, 2);
    if (t < NT - 2)      { asm volatile("s_waitcnt vmcnt(6)" ::: "memory"); }
    else if (t == NT - 2){ asm volatile("s_waitcnt vmcnt(0)" ::: "memory"); }
    GSB(); GBAR(); GLGKM0(); GSB();
    __builtin_amdgcn_s_setprio(1); MM(4, 0, b0); __builtin_amdgcn_s_setprio(0);
    GSB(); GBAR();
  }

  // epilogue: C/D frag mapping col=lr, row=lk*4+rr
  #pragma unroll
  for (int mi = 0; mi < 8; ++mi){
    const int rowb = bm*256 + (mi >> 2)*128 + wm*64 + (mi & 3)*16 + lk*4;
    #pragma unroll
    for (int ni = 0; ni < 4; ++ni){
      const int col = bn*256 + (ni >> 1)*128 + wn*32 + (ni & 1)*16 + lr;
      #pragma unroll
      for (int rr = 0; rr < 4; ++rr){
        const int row = rowb + rr;
        if (FUSE == 0){
          outb[(size_t)row*NOUT + col] = f2bf(acc[mi][ni][rr]);
        } else {
          outf[(size_t)row*NOUT + col] = acc[mi][ni][rr] + Dv[col]*U[(size_t)row*NOUT + col];
        }
      }
    }
  }
#undef STAGE
#undef RD_A
#undef RD_B
#undef MM
}

// ---------------- scan phase 1: chunk-local end states ----------------
__global__ __launch_bounds__(64) void scan_p1(const u16* __restrict__ xbf, float* __restrict__ E,
                                              const float* __restrict__ gam, const float* __restrict__ th)
{
  const int g = blockIdx.x, c = blockIdx.y, l = threadIdx.x;
  const int head = g*4 + (l >> 4), p = l & 15;
  const float gamma = gam[head];
  const float theta = th[head*16 + p];
  const float cs = cosf(theta), sn = sinf(theta);
  float he = 0.f, ho = 0.f;
  const int off = g*128 + (l >> 4)*32 + p*2;
  const u16* px = xbf + (size_t)c*LCH*MD + off;
  #pragma unroll 4
  for (int t = 0; t < LCH; ++t){
    const u32 w = *(const u32*)px;
    const float xe = __uint_as_float(w << 16);
    const float xo = __uint_as_float(w & 0xffff0000u);
    const float te = fmaf(cs, he, -sn*ho);
    const float to = fmaf(sn, he,  cs*ho);
    he = fmaf(gamma, te, xe);
    ho = fmaf(gamma, to, xo);
    px += MD;
  }
  *(float2*)(E + (size_t)c*MD + off) = make_float2(he, ho);
}

// ---------------- scan phase 2: per-head combine over chunks; E[c] <- exclusive carry ----------------
__global__ __launch_bounds__(64) void scan_p2(float* __restrict__ E,
                                              const float* __restrict__ gam, const float* __restrict__ th)
{
  const int g = blockIdx.x, l = threadIdx.x;
  const int head = g*4 + (l >> 4), p = l & 15;
  const float gamma = gam[head];
  const float theta = th[head*16 + p];
  const float gL = expf((float)LCH * logf(gamma));
  const float aL = (float)LCH * theta;
  const float cL = cosf(aL), sL = sinf(aL);
  float ce = 0.f, co = 0.f;
  const int off = g*128 + (l >> 4)*32 + p*2;
  for (int c = 0; c < NCH; ++c){
    float2* Ep = (float2*)(E + (size_t)c*MD + off);
    const float2 e = *Ep;
    *Ep = make_float2(ce, co);
    const float te = gL * (cL*ce - sL*co);
    const float to = gL * (sL*ce + cL*co);
    ce = te + e.x;
    co = to + e.y;
  }
}

// ---------------- scan phase 3: replay chunks from carry, write hidden (bf16) ----------------
__global__ __launch_bounds__(64) void scan_p3(const u16* __restrict__ xbf, const float* __restrict__ E,
                                              u16* __restrict__ hid,
                                              const float* __restrict__ gam, const float* __restrict__ th)
{
  const int g = blockIdx.x, c = blockIdx.y, l = threadIdx.x;
  const int head = g*4 + (l >> 4), p = l & 15;
  const float gamma = gam[head];
  const float theta = th[head*16 + p];
  const float cs = cosf(theta), sn = sinf(theta);
  const int off = g*128 + (l >> 4)*32 + p*2;
  const float2 cr = *(const float2*)(E + (size_t)c*MD + off);
  float he = cr.x, ho = cr.y;
  const u16* px = xbf + (size_t)c*LCH*MD + off;
  u16* ph = hid + (size_t)c*LCH*MD + off;
  #pragma unroll 4
  for (int t = 0; t < LCH; ++t){
    const u32 w = *(const u32*)px;
    const float xe = __uint_as_float(w << 16);
    const float xo = __uint_as_float(w & 0xffff0000u);
    const float te = fmaf(cs, he, -sn*ho);
    const float to = fmaf(sn, he,  cs*ho);
    he = fmaf(gamma, te, xe);
    ho = fmaf(gamma, to, xo);
    *(u32*)ph = (u32)f2bf(he) | ((u32)f2bf(ho) << 16);
    px += MD;
    ph += MD;
  }
}

extern "C" void kernel_launch(void* const* d_in, const int* in_sizes, int n_in,
                              void* d_out, int out_size, void* d_ws, size_t ws_size,
                              hipStream_t stream) {
  const float* U  = (const float*)d_in[0];   // (T, MD)
  const float* TH = (const float*)d_in[1];   // (H, 16)
  const float* Mm = (const float*)d_in[2];   // (H, 32, 32)
  const float* B  = (const float*)d_in[3];   // (H, 32, MD)
  const float* C  = (const float*)d_in[4];   // (MD, MD)
  const float* Dv = (const float*)d_in[5];   // (MD,)
  const float* GL = (const float*)d_in[6];   // (H, 1)
  float* Y = (float*)d_out;

  char* w = (char*)d_ws;
  u16*   u_bf = (u16*)(w);                       // 32 MB
  u16*   x_bf = (u16*)(w + 33554432);            // 32 MB
  u16*   BPw  = (u16*)(w + 67108864);            // 8 MB
  u16*   CPw  = (u16*)(w + 75497472);            // 8 MB
  float* Pw   = (float*)(w + 83886080);          // 256 KB
  float* Ew   = (float*)(w + 84148224);          // 512 KB
  float* gam  = (float*)(w + 84672512);
  float* xiw  = (float*)(w + 84672768);
  u16*   hid  = u_bf;                            // alias: u_bf dead after GEMM1

  k_prep<<<NH, 256, 0, stream>>>(B, GL, gam, xiw);
  k_expm<<<NH, dim3(32, 32), 0, stream>>>(Mm, Pw);
  k_bp<<<dim3(8, NH), 256, 0, stream>>>(B, Pw, xiw, BPw);
  k_cp<<<dim3(32, NH), 256, 0, stream>>>(C, Pw, CPw);
  k_cvt<<<4096, 256, 0, stream>>>(U, u_bf, (T_LEN*MD)/4);

  gemm256<0><<<dim3(MD/256, T_LEN/256), 512, 0, stream>>>(
      u_bf, BPw, x_bf, nullptr, nullptr, nullptr);

  scan_p1<<<dim3(16, NCH), 64, 0, stream>>>(x_bf, Ew, gam, TH);
  scan_p2<<<16, 64, 0, stream>>>(Ew, gam, TH);
  scan_p3<<<dim3(16, NCH), 64, 0, stream>>>(x_bf, Ew, hid, gam, TH);

  gemm256<1><<<dim3(MD/256, T_LEN/256), 512, 0, stream>>>(
      hid, CPw, nullptr, Y, Dv, U);
}

// Round 5
// 382.274 us; speedup vs baseline: 1.4817x; 1.2631x over previous
//
#include <hip/hip_runtime.h>

typedef unsigned short u16;
typedef unsigned int u32;

#define T_LEN 8192
#define MD    2048
#define NH    64
#define NCH   64
#define LCH   128   // T_LEN / NCH

typedef __attribute__((ext_vector_type(8))) short bf16x8;
typedef __attribute__((ext_vector_type(4))) float f32x4;

__device__ __forceinline__ u16 f2bf(float f){
  u32 u = __float_as_uint(f);
  u += 0x7fffu + ((u >> 16) & 1u);
  return (u16)(u >> 16);
}

// ---------------- setup: partial sum-of-squares of B (1024 blocks, float4) ----------------
__global__ __launch_bounds__(256) void k_prep_part(const float* __restrict__ B,
                                                   float* __restrict__ partial)
{
  const int s = blockIdx.x, h = blockIdx.y, tid = threadIdx.x;
  const float4* Bh = (const float4*)(B + (size_t)h * 32 * MD) + s * 1024;
  float acc = 0.f;
  #pragma unroll
  for (int i = 0; i < 4; ++i){
    float4 v = Bh[tid + i * 256];
    acc += v.x*v.x + v.y*v.y + v.z*v.z + v.w*v.w;
  }
  for (int o = 32; o; o >>= 1) acc += __shfl_down(acc, o);
  __shared__ float red[4];
  if ((tid & 63) == 0) red[tid >> 6] = acc;
  __syncthreads();
  if (tid == 0) partial[h * 16 + s] = red[0] + red[1] + red[2] + red[3];
}

// ---------------- finalize gamma, xi ----------------
__global__ __launch_bounds__(64) void k_final(const float* __restrict__ partial,
                                              const float* __restrict__ gamma_log,
                                              float* __restrict__ gam,
                                              float* __restrict__ xi)
{
  const int h = threadIdx.x;
  float t = 0.f;
  #pragma unroll
  for (int s = 0; s < 16; ++s) t += partial[h * 16 + s];
  const float g = expf(-expf(gamma_log[h]));
  gam[h] = g;
  xi[h] = sqrtf((1.f - g * g) / t);
}

// ---------------- P = expm(M - M^T), one 32x32 block per head ----------------
__global__ __launch_bounds__(1024) void k_expm(const float* __restrict__ Mp,
                                               float* __restrict__ P)
{
  const int h = blockIdx.x;
  const int j = threadIdx.x, i = threadIdx.y;
  const int tid = i * 32 + j;
  __shared__ float X[32][32], Tm[32][32], S[32][32];
  __shared__ float red[16];
  __shared__ float s_fn2;
  const float* Mh = Mp + (size_t)h * 1024;
  float a = Mh[i * 32 + j] - Mh[j * 32 + i];
  float v = a * a;
  for (int o = 32; o; o >>= 1) v += __shfl_down(v, o);
  if ((tid & 63) == 0) red[tid >> 6] = v;
  __syncthreads();
  if (tid == 0){
    float t = 0.f;
    for (int q = 0; q < 16; ++q) t += red[q];
    s_fn2 = t;
  }
  __syncthreads();
  const float fn = sqrtf(s_fn2);
  int sc = 0; float t = fn;
  while (t > 0.25f && sc < 24){ t *= 0.5f; ++sc; }
  const float scale = exp2f((float)(-sc));
  X[i][j] = a * scale;
  Tm[i][j] = a * scale;
  S[i][j] = a * scale + (i == j ? 1.f : 0.f);
  __syncthreads();
  for (int k = 2; k <= 13; ++k){
    float acc = 0.f;
    #pragma unroll
    for (int m = 0; m < 32; ++m) acc = fmaf(Tm[i][m], X[m][j], acc);
    acc *= (1.f / (float)k);
    __syncthreads();
    Tm[i][j] = acc;
    S[i][j] += acc;
    __syncthreads();
  }
  for (int q = 0; q < sc; ++q){
    float acc = 0.f;
    #pragma unroll
    for (int m = 0; m < 32; ++m) acc = fmaf(S[i][m], S[m][j], acc);
    __syncthreads();
    S[i][j] = acc;
    __syncthreads();
  }
  P[(size_t)h * 1024 + i * 32 + j] = S[i][j];
}

// ---------------- BP[h*32+n][i] = xi_h * sum_m P[h][m][n] * B[h][m][i] (bf16) ----------------
__global__ __launch_bounds__(256) void k_bp(const float* __restrict__ B,
                                            const float* __restrict__ P,
                                            const float* __restrict__ xi,
                                            u16* __restrict__ BP)
{
  const int h = blockIdx.y;
  const int i = blockIdx.x * 256 + threadIdx.x;
  __shared__ float Pl[32][32];
  for (int q = threadIdx.x; q < 1024; q += 256) ((float*)Pl)[q] = P[(size_t)h*1024 + q];
  __syncthreads();
  const float x = xi[h];
  float breg[32];
  #pragma unroll
  for (int m = 0; m < 32; ++m) breg[m] = B[(size_t)h*32*MD + (size_t)m*MD + i];
  for (int n = 0; n < 32; ++n){
    float acc = 0.f;
    #pragma unroll
    for (int m = 0; m < 32; ++m) acc = fmaf(Pl[m][n], breg[m], acc);
    BP[(size_t)(h*32 + n)*MD + i] = f2bf(x * acc);
  }
}

// ---------------- CP[m][h*32+i] = sum_n C[m][h*32+n] * P[h][n][i] (bf16) ----------------
__global__ __launch_bounds__(256) void k_cp(const float* __restrict__ C,
                                            const float* __restrict__ P,
                                            u16* __restrict__ CP)
{
  const int h = blockIdx.y;
  const int m0 = blockIdx.x * 64;
  __shared__ float Pl[32][32];
  for (int q = threadIdx.x; q < 1024; q += 256) ((float*)Pl)[q] = P[(size_t)h*1024 + q];
  __syncthreads();
  const int ml = threadIdx.x >> 5, ii = threadIdx.x & 31;
  for (int sub = 0; sub < 8; ++sub){
    const int m = m0 + sub*8 + ml;
    const float* Cm = C + (size_t)m*MD + h*32;
    float acc = 0.f;
    #pragma unroll
    for (int n = 0; n < 32; ++n) acc = fmaf(Cm[n], Pl[n][ii], acc);
    CP[(size_t)m*MD + h*32 + ii] = f2bf(acc);
  }
}

// ---------------- f32 -> bf16 convert ----------------
__global__ __launch_bounds__(256) void k_cvt(const float* __restrict__ in, u16* __restrict__ out, int n4)
{
  const int idx = blockIdx.x * 256 + threadIdx.x;
  const int stride = gridDim.x * 256;
  for (int i = idx; i < n4; i += stride){
    float4 v = ((const float4*)in)[i];
    ushort4 o;
    o.x = f2bf(v.x); o.y = f2bf(v.y); o.z = f2bf(v.z); o.w = f2bf(v.w);
    ((ushort4*)out)[i] = o;
  }
}

// ================= 256x256 8-phase bf16 GEMM: out[M,N] = A[M,K] * W[N,K]^T =================
// (unchanged from R4 — verified passing, bank-conflict-free)
#define GBAR() __builtin_amdgcn_s_barrier()
#define GSB()  __builtin_amdgcn_sched_barrier(0)
#define GLGKM0() asm volatile("s_waitcnt lgkmcnt(0)" ::: "memory")

template<int FUSE>
__global__ __launch_bounds__(512, 1) void gemm256(
    const u16* __restrict__ A, const u16* __restrict__ W,
    u16* __restrict__ outb, float* __restrict__ outf,
    const float* __restrict__ Dv, const float* __restrict__ U)
{
  constexpr int K = 2048, NOUT = 2048, NT = K / 64;
  __shared__ u16 sm[65536];                 // 128 KiB
  const int tid = threadIdx.x;
  const int lane = tid & 63;
  const int wv = tid >> 6;
  const int wm = wv >> 2, wn = wv & 3;      // 2 x 4 waves, per-wave out 128x64
  const int lr = lane & 15, lk = lane >> 4;

  const int bid = blockIdx.y * gridDim.x + blockIdx.x;
  const int swz = (bid & 7) * 32 + (bid >> 3);
  const int bn = swz & 7, bm = swz >> 3;

  const u16* Ablk = A + (size_t)bm * 256 * K;
  const u16* Wblk = W + (size_t)bn * 256 * K;

  const int r0 = tid >> 3;
  const size_t gthr = (size_t)r0 * K + (size_t)(((tid & 7) ^ (r0 & 7)) << 3);

  const int sl0 = ((lk ^ (lr & 7)) << 3);
  const int sl1 = (((4 + lk) ^ (lr & 7)) << 3);

  f32x4 acc[8][4] = {};
  bf16x8 a[4][2], b0[2][2], b1[2][2];

#define STAGE(tt, y) do { \
    const int p_ = (tt) & 1; \
    const int rb_ = ((y) >= 2) ? 128 : 0; \
    const bool isA_ = ((y) == 0) || ((y) == 3); \
    const u16* gb_ = isA_ ? Ablk : Wblk; \
    u16* lb_ = sm + p_*32768 + (isA_ ? 0 : 16384); \
    _Pragma("unroll") for (int i_ = 0; i_ < 2; ++i_){ \
      const u16* g_ = gb_ + gthr + (size_t)(rb_ + i_*64) * K + (size_t)(tt) * 64; \
      u16* l_ = lb_ + (rb_ + i_*64 + wv*8) * 64; \
      __builtin_amdgcn_global_load_lds( \
        (const __attribute__((address_space(1))) void*)g_, \
        (__attribute__((address_space(3))) void*)l_, 16, 0, 0); \
    } \
  } while(0)

#define RD_A(qm) do { \
    const u16* sa_ = sm + p*32768 + ((qm)*128 + wm*64 + lr) * 64; \
    _Pragma("unroll") for (int mi_ = 0; mi_ < 4; ++mi_){ \
      a[mi_][0] = *(const bf16x8*)(sa_ + mi_*1024 + sl0); \
      a[mi_][1] = *(const bf16x8*)(sa_ + mi_*1024 + sl1); } \
  } while(0)

#define RD_B(qn, breg) do { \
    const u16* sb_ = sm + p*32768 + 16384 + ((qn)*128 + wn*32 + lr) * 64; \
    _Pragma("unroll") for (int ni_ = 0; ni_ < 2; ++ni_){ \
      breg[ni_][0] = *(const bf16x8*)(sb_ + ni_*1024 + sl0); \
      breg[ni_][1] = *(const bf16x8*)(sb_ + ni_*1024 + sl1); } \
  } while(0)

#define MM(mo, no, breg) do { \
    _Pragma("unroll") for (int mi_ = 0; mi_ < 4; ++mi_) \
    _Pragma("unroll") for (int ni_ = 0; ni_ < 2; ++ni_){ \
      acc[(mo)+mi_][(no)+ni_] = __builtin_amdgcn_mfma_f32_16x16x32_bf16(a[mi_][0], breg[ni_][0], acc[(mo)+mi_][(no)+ni_], 0, 0, 0); \
      acc[(mo)+mi_][(no)+ni_] = __builtin_amdgcn_mfma_f32_16x16x32_bf16(a[mi_][1], breg[ni_][1], acc[(mo)+mi_][(no)+ni_], 0, 0, 0); } \
  } while(0)

  STAGE(0, 0); STAGE(0, 1); STAGE(0, 2); STAGE(0, 3);
  STAGE(1, 0); STAGE(1, 1); STAGE(1, 2);
  asm volatile("s_waitcnt vmcnt(6)" ::: "memory");
  GSB(); GBAR();

  for (int t = 0; t < NT; ++t){
    const int p = t & 1;
    RD_A(0); RD_B(0, b0);
    if (t + 1 < NT) STAGE(t + 1, 3);
    GSB(); GBAR(); GLGKM0(); GSB();
    __builtin_amdgcn_s_setprio(1); MM(0, 0, b0); __builtin_amdgcn_s_setprio(0);
    GSB(); GBAR();
    RD_B(1, b1);
    if (t + 2 < NT) STAGE(t + 2, 0);
    GSB(); GBAR(); GLGKM0(); GSB();
    __builtin_amdgcn_s_setprio(1); MM(0, 2, b1); __builtin_amdgcn_s_setprio(0);
    GSB(); GBAR();
    RD_A(1);
    if (t + 2 < NT) STAGE(t + 2, 1);
    GSB(); GBAR(); GLGKM0(); GSB();
    __builtin_amdgcn_s_setprio(1); MM(4, 2, b1); __builtin_amdgcn_s_setprio(0);
    GSB(); GBAR();
    if (t + 2 < NT) STAGE(t + 2, 2);
    if (t < NT - 2)      { asm volatile("s_waitcnt vmcnt(6)" ::: "memory"); }
    else if (t == NT - 2){ asm volatile("s_waitcnt vmcnt(0)" ::: "memory"); }
    GSB(); GBAR(); GLGKM0(); GSB();
    __builtin_amdgcn_s_setprio(1); MM(4, 0, b0); __builtin_amdgcn_s_setprio(0);
    GSB(); GBAR();
  }

  #pragma unroll
  for (int mi = 0; mi < 8; ++mi){
    const int rowb = bm*256 + (mi >> 2)*128 + wm*64 + (mi & 3)*16 + lk*4;
    #pragma unroll
    for (int ni = 0; ni < 4; ++ni){
      const int col = bn*256 + (ni >> 1)*128 + wn*32 + (ni & 1)*16 + lr;
      #pragma unroll
      for (int rr = 0; rr < 4; ++rr){
        const int row = rowb + rr;
        if (FUSE == 0){
          outb[(size_t)row*NOUT + col] = f2bf(acc[mi][ni][rr]);
        } else {
          outf[(size_t)row*NOUT + col] = acc[mi][ni][rr] + Dv[col]*U[(size_t)row*NOUT + col];
        }
      }
    }
  }
#undef STAGE
#undef RD_A
#undef RD_B
#undef MM
}

// ---------------- scan phase 1: chunk-local end states ----------------
__global__ __launch_bounds__(64) void scan_p1(const u16* __restrict__ xbf, float* __restrict__ E,
                                              const float* __restrict__ gam, const float* __restrict__ th)
{
  const int g = blockIdx.x, c = blockIdx.y, l = threadIdx.x;
  const int head = g*4 + (l >> 4), p = l & 15;
  const float gamma = gam[head];
  const float theta = th[head*16 + p];
  const float cs = cosf(theta), sn = sinf(theta);
  float he = 0.f, ho = 0.f;
  const int off = g*128 + (l >> 4)*32 + p*2;
  const u16* px = xbf + (size_t)c*LCH*MD + off;
  #pragma unroll 4
  for (int t = 0; t < LCH; ++t){
    const u32 w = *(const u32*)px;
    const float xe = __uint_as_float(w << 16);
    const float xo = __uint_as_float(w & 0xffff0000u);
    const float te = fmaf(cs, he, -sn*ho);
    const float to = fmaf(sn, he,  cs*ho);
    he = fmaf(gamma, te, xe);
    ho = fmaf(gamma, to, xo);
    px += MD;
  }
  *(float2*)(E + (size_t)c*MD + off) = make_float2(he, ho);
}

// ---------------- scan phase 2: per-head combine over chunks; E[c] <- exclusive carry ----------------
__global__ __launch_bounds__(64) void scan_p2(float* __restrict__ E,
                                              const float* __restrict__ gam, const float* __restrict__ th)
{
  const int g = blockIdx.x, l = threadIdx.x;
  const int head = g*4 + (l >> 4), p = l & 15;
  const float gamma = gam[head];
  const float theta = th[head*16 + p];
  const float gL = expf((float)LCH * logf(gamma));
  const float aL = (float)LCH * theta;
  const float cL = cosf(aL), sL = sinf(aL);
  float ce = 0.f, co = 0.f;
  const int off = g*128 + (l >> 4)*32 + p*2;
  for (int c = 0; c < NCH; ++c){
    float2* Ep = (float2*)(E + (size_t)c*MD + off);
    const float2 e = *Ep;
    *Ep = make_float2(ce, co);
    const float te = gL * (cL*ce - sL*co);
    const float to = gL * (sL*ce + cL*co);
    ce = te + e.x;
    co = to + e.y;
  }
}

// ---------------- scan phase 3: replay chunks from carry, write hidden (bf16) ----------------
__global__ __launch_bounds__(64) void scan_p3(const u16* __restrict__ xbf, const float* __restrict__ E,
                                              u16* __restrict__ hid,
                                              const float* __restrict__ gam, const float* __restrict__ th)
{
  const int g = blockIdx.x, c = blockIdx.y, l = threadIdx.x;
  const int head = g*4 + (l >> 4), p = l & 15;
  const float gamma = gam[head];
  const float theta = th[head*16 + p];
  const float cs = cosf(theta), sn = sinf(theta);
  const int off = g*128 + (l >> 4)*32 + p*2;
  const float2 cr = *(const float2*)(E + (size_t)c*MD + off);
  float he = cr.x, ho = cr.y;
  const u16* px = xbf + (size_t)c*LCH*MD + off;
  u16* ph = hid + (size_t)c*LCH*MD + off;
  #pragma unroll 4
  for (int t = 0; t < LCH; ++t){
    const u32 w = *(const u32*)px;
    const float xe = __uint_as_float(w << 16);
    const float xo = __uint_as_float(w & 0xffff0000u);
    const float te = fmaf(cs, he, -sn*ho);
    const float to = fmaf(sn, he,  cs*ho);
    he = fmaf(gamma, te, xe);
    ho = fmaf(gamma, to, xo);
    *(u32*)ph = (u32)f2bf(he) | ((u32)f2bf(ho) << 16);
    px += MD;
    ph += MD;
  }
}

extern "C" void kernel_launch(void* const* d_in, const int* in_sizes, int n_in,
                              void* d_out, int out_size, void* d_ws, size_t ws_size,
                              hipStream_t stream) {
  const float* U  = (const float*)d_in[0];   // (T, MD)
  const float* TH = (const float*)d_in[1];   // (H, 16)
  const float* Mm = (const float*)d_in[2];   // (H, 32, 32)
  const float* B  = (const float*)d_in[3];   // (H, 32, MD)
  const float* C  = (const float*)d_in[4];   // (MD, MD)
  const float* Dv = (const float*)d_in[5];   // (MD,)
  const float* GL = (const float*)d_in[6];   // (H, 1)
  float* Y = (float*)d_out;

  char* w = (char*)d_ws;
  u16*   u_bf = (u16*)(w);                       // 32 MB
  u16*   x_bf = (u16*)(w + 33554432);            // 32 MB
  u16*   BPw  = (u16*)(w + 67108864);            // 8 MB
  u16*   CPw  = (u16*)(w + 75497472);            // 8 MB
  float* Pw   = (float*)(w + 83886080);          // 256 KB
  float* Ew   = (float*)(w + 84148224);          // 512 KB
  float* gam  = (float*)(w + 84672512);
  float* xiw  = (float*)(w + 84672768);
  float* part = (float*)(w + 84673024);          // 4 KB partials
  u16*   hid  = u_bf;                            // alias: u_bf dead after GEMM1

  k_prep_part<<<dim3(16, NH), 256, 0, stream>>>(B, part);
  k_final<<<1, 64, 0, stream>>>(part, GL, gam, xiw);
  k_expm<<<NH, dim3(32, 32), 0, stream>>>(Mm, Pw);
  k_bp<<<dim3(8, NH), 256, 0, stream>>>(B, Pw, xiw, BPw);
  k_cp<<<dim3(32, NH), 256, 0, stream>>>(C, Pw, CPw);
  k_cvt<<<4096, 256, 0, stream>>>(U, u_bf, (T_LEN*MD)/4);

  gemm256<0><<<dim3(MD/256, T_LEN/256), 512, 0, stream>>>(
      u_bf, BPw, x_bf, nullptr, nullptr, nullptr);

  scan_p1<<<dim3(16, NCH), 64, 0, stream>>>(x_bf, Ew, gam, TH);
  scan_p2<<<16, 64, 0, stream>>>(Ew, gam, TH);
  scan_p3<<<dim3(16, NCH), 64, 0, stream>>>(x_bf, Ew, hid, gam, TH);

  gemm256<1><<<dim3(MD/256, T_LEN/256), 512, 0, stream>>>(
      hid, CPw, nullptr, Y, Dv, U);
}

// Round 6
// 353.704 us; speedup vs baseline: 1.6014x; 1.0808x over previous
//
#include <hip/hip_runtime.h>

typedef unsigned short u16;
typedef unsigned int u32;

#define T_LEN 8192
#define MD    2048
#define NH    64
#define NCH   256
#define LCH   32    // T_LEN / NCH

typedef __attribute__((ext_vector_type(8))) short bf16x8;
typedef __attribute__((ext_vector_type(4))) float f32x4;

__device__ __forceinline__ u16 f2bf(float f){
  u32 u = __float_as_uint(f);
  u += 0x7fffu + ((u >> 16) & 1u);
  return (u16)(u >> 16);
}

// ---------------- setup: partial sum-of-squares of B (1024 blocks, float4) ----------------
__global__ __launch_bounds__(256) void k_prep_part(const float* __restrict__ B,
                                                   float* __restrict__ partial)
{
  const int s = blockIdx.x, h = blockIdx.y, tid = threadIdx.x;
  const float4* Bh = (const float4*)(B + (size_t)h * 32 * MD) + s * 1024;
  float acc = 0.f;
  #pragma unroll
  for (int i = 0; i < 4; ++i){
    float4 v = Bh[tid + i * 256];
    acc += v.x*v.x + v.y*v.y + v.z*v.z + v.w*v.w;
  }
  for (int o = 32; o; o >>= 1) acc += __shfl_down(acc, o);
  __shared__ float red[4];
  if ((tid & 63) == 0) red[tid >> 6] = acc;
  __syncthreads();
  if (tid == 0) partial[h * 16 + s] = red[0] + red[1] + red[2] + red[3];
}

// ---------------- P = expm(M - M^T), one 32x32 block per head ----------------
__global__ __launch_bounds__(1024) void k_expm(const float* __restrict__ Mp,
                                               float* __restrict__ P)
{
  const int h = blockIdx.x;
  const int j = threadIdx.x, i = threadIdx.y;
  const int tid = i * 32 + j;
  __shared__ float X[32][32], Tm[32][32], S[32][32];
  __shared__ float red[16];
  __shared__ float s_fn2;
  const float* Mh = Mp + (size_t)h * 1024;
  float a = Mh[i * 32 + j] - Mh[j * 32 + i];
  float v = a * a;
  for (int o = 32; o; o >>= 1) v += __shfl_down(v, o);
  if ((tid & 63) == 0) red[tid >> 6] = v;
  __syncthreads();
  if (tid == 0){
    float t = 0.f;
    for (int q = 0; q < 16; ++q) t += red[q];
    s_fn2 = t;
  }
  __syncthreads();
  const float fn = sqrtf(s_fn2);
  int sc = 0; float t = fn;
  while (t > 0.25f && sc < 24){ t *= 0.5f; ++sc; }
  const float scale = exp2f((float)(-sc));
  X[i][j] = a * scale;
  Tm[i][j] = a * scale;
  S[i][j] = a * scale + (i == j ? 1.f : 0.f);
  __syncthreads();
  for (int k = 2; k <= 13; ++k){
    float acc = 0.f;
    #pragma unroll
    for (int m = 0; m < 32; ++m) acc = fmaf(Tm[i][m], X[m][j], acc);
    acc *= (1.f / (float)k);
    __syncthreads();
    Tm[i][j] = acc;
    S[i][j] += acc;
    __syncthreads();
  }
  for (int q = 0; q < sc; ++q){
    float acc = 0.f;
    #pragma unroll
    for (int m = 0; m < 32; ++m) acc = fmaf(S[i][m], S[m][j], acc);
    __syncthreads();
    S[i][j] = acc;
    __syncthreads();
  }
  P[(size_t)h * 1024 + i * 32 + j] = S[i][j];
}

// ---------------- BP[h*32+n][i] = xi_h * sum_m P[h][m][n] * B[h][m][i] (bf16) ----------------
// xi recomputed per block from the 16 partials (k_final folded in).
__global__ __launch_bounds__(256) void k_bp(const float* __restrict__ B,
                                            const float* __restrict__ P,
                                            const float* __restrict__ partial,
                                            const float* __restrict__ GL,
                                            u16* __restrict__ BP)
{
  const int h = blockIdx.y;
  const int i = blockIdx.x * 256 + threadIdx.x;
  __shared__ float Pl[32][32];
  for (int q = threadIdx.x; q < 1024; q += 256) ((float*)Pl)[q] = P[(size_t)h*1024 + q];
  __syncthreads();
  float tsum = 0.f;
  #pragma unroll
  for (int s = 0; s < 16; ++s) tsum += partial[h*16 + s];
  const float g = expf(-expf(GL[h]));
  const float x = sqrtf((1.f - g*g) / tsum);
  float breg[32];
  #pragma unroll
  for (int m = 0; m < 32; ++m) breg[m] = B[(size_t)h*32*MD + (size_t)m*MD + i];
  for (int n = 0; n < 32; ++n){
    float acc = 0.f;
    #pragma unroll
    for (int m = 0; m < 32; ++m) acc = fmaf(Pl[m][n], breg[m], acc);
    BP[(size_t)(h*32 + n)*MD + i] = f2bf(x * acc);
  }
}

// ---------------- CP[m][h*32+i] = sum_n C[m][h*32+n] * P[h][n][i] (bf16) ----------------
// one thread per m; float4 loads of C row-slice; packed u16 stores.
__global__ __launch_bounds__(256) void k_cp(const float* __restrict__ C,
                                            const float* __restrict__ P,
                                            u16* __restrict__ CP)
{
  const int h = blockIdx.y;
  const int m = blockIdx.x * 256 + threadIdx.x;   // grid.x = 8
  __shared__ float Pl[32][32];
  for (int q = threadIdx.x; q < 1024; q += 256) ((float*)Pl)[q] = P[(size_t)h*1024 + q];
  __syncthreads();
  float cr[32];
  const float4* Cm4 = (const float4*)(C + (size_t)m*MD + h*32);
  #pragma unroll
  for (int q = 0; q < 8; ++q){
    float4 v = Cm4[q];
    cr[q*4+0] = v.x; cr[q*4+1] = v.y; cr[q*4+2] = v.z; cr[q*4+3] = v.w;
  }
  u32 ow[16];
  #pragma unroll
  for (int i2 = 0; i2 < 16; ++i2){
    float a0 = 0.f, a1 = 0.f;
    #pragma unroll
    for (int n = 0; n < 32; ++n){
      a0 = fmaf(cr[n], Pl[n][i2*2],   a0);
      a1 = fmaf(cr[n], Pl[n][i2*2+1], a1);
    }
    ow[i2] = (u32)f2bf(a0) | ((u32)f2bf(a1) << 16);
  }
  uint4* dst = (uint4*)(CP + (size_t)m*MD + h*32);
  #pragma unroll
  for (int q = 0; q < 4; ++q)
    dst[q] = make_uint4(ow[q*4], ow[q*4+1], ow[q*4+2], ow[q*4+3]);
}

// ---------------- f32 -> bf16 convert ----------------
__global__ __launch_bounds__(256) void k_cvt(const float* __restrict__ in, u16* __restrict__ out, int n4)
{
  const int idx = blockIdx.x * 256 + threadIdx.x;
  const int stride = gridDim.x * 256;
  for (int i = idx; i < n4; i += stride){
    float4 v = ((const float4*)in)[i];
    ushort4 o;
    o.x = f2bf(v.x); o.y = f2bf(v.y); o.z = f2bf(v.z); o.w = f2bf(v.w);
    ((ushort4*)out)[i] = o;
  }
}

// ================= 256x256 8-phase bf16 GEMM: out[M,N] = A[M,K] * W[N,K]^T =================
// K-loop unchanged (verified R4/R5, bank-conflict-free). New: LDS-transposed coalesced
// epilogue; FUSE==1 adds D[col]*u (u read as bf16 from Ubf).
#define GBAR() __builtin_amdgcn_s_barrier()
#define GSB()  __builtin_amdgcn_sched_barrier(0)
#define GLGKM0() asm volatile("s_waitcnt lgkmcnt(0)" ::: "memory")

template<int FUSE>
__global__ __launch_bounds__(512, 1) void gemm256(
    const u16* __restrict__ A, const u16* __restrict__ W,
    u16* __restrict__ outb, float* __restrict__ outf,
    const float* __restrict__ Dv, const u16* __restrict__ Ubf)
{
  constexpr int K = 2048, NOUT = 2048, NT = K / 64;
  __shared__ u16 sm[65536];                 // 128 KiB
  const int tid = threadIdx.x;
  const int lane = tid & 63;
  const int wv = tid >> 6;
  const int wm = wv >> 2, wn = wv & 3;      // 2 x 4 waves, per-wave out 128x64
  const int lr = lane & 15, lk = lane >> 4;

  const int bid = blockIdx.y * gridDim.x + blockIdx.x;
  const int swz = (bid & 7) * 32 + (bid >> 3);
  const int bn = swz & 7, bm = swz >> 3;

  const u16* Ablk = A + (size_t)bm * 256 * K;
  const u16* Wblk = W + (size_t)bn * 256 * K;

  const int r0 = tid >> 3;
  const size_t gthr = (size_t)r0 * K + (size_t)(((tid & 7) ^ (r0 & 7)) << 3);

  const int sl0 = ((lk ^ (lr & 7)) << 3);
  const int sl1 = (((4 + lk) ^ (lr & 7)) << 3);

  f32x4 acc[8][4] = {};
  bf16x8 a[4][2], b0[2][2], b1[2][2];

#define STAGE(tt, y) do { \
    const int p_ = (tt) & 1; \
    const int rb_ = ((y) >= 2) ? 128 : 0; \
    const bool isA_ = ((y) == 0) || ((y) == 3); \
    const u16* gb_ = isA_ ? Ablk : Wblk; \
    u16* lb_ = sm + p_*32768 + (isA_ ? 0 : 16384); \
    _Pragma("unroll") for (int i_ = 0; i_ < 2; ++i_){ \
      const u16* g_ = gb_ + gthr + (size_t)(rb_ + i_*64) * K + (size_t)(tt) * 64; \
      u16* l_ = lb_ + (rb_ + i_*64 + wv*8) * 64; \
      __builtin_amdgcn_global_load_lds( \
        (const __attribute__((address_space(1))) void*)g_, \
        (__attribute__((address_space(3))) void*)l_, 16, 0, 0); \
    } \
  } while(0)

#define RD_A(qm) do { \
    const u16* sa_ = sm + p*32768 + ((qm)*128 + wm*64 + lr) * 64; \
    _Pragma("unroll") for (int mi_ = 0; mi_ < 4; ++mi_){ \
      a[mi_][0] = *(const bf16x8*)(sa_ + mi_*1024 + sl0); \
      a[mi_][1] = *(const bf16x8*)(sa_ + mi_*1024 + sl1); } \
  } while(0)

#define RD_B(qn, breg) do { \
    const u16* sb_ = sm + p*32768 + 16384 + ((qn)*128 + wn*32 + lr) * 64; \
    _Pragma("unroll") for (int ni_ = 0; ni_ < 2; ++ni_){ \
      breg[ni_][0] = *(const bf16x8*)(sb_ + ni_*1024 + sl0); \
      breg[ni_][1] = *(const bf16x8*)(sb_ + ni_*1024 + sl1); } \
  } while(0)

#define MM(mo, no, breg) do { \
    _Pragma("unroll") for (int mi_ = 0; mi_ < 4; ++mi_) \
    _Pragma("unroll") for (int ni_ = 0; ni_ < 2; ++ni_){ \
      acc[(mo)+mi_][(no)+ni_] = __builtin_amdgcn_mfma_f32_16x16x32_bf16(a[mi_][0], breg[ni_][0], acc[(mo)+mi_][(no)+ni_], 0, 0, 0); \
      acc[(mo)+mi_][(no)+ni_] = __builtin_amdgcn_mfma_f32_16x16x32_bf16(a[mi_][1], breg[ni_][1], acc[(mo)+mi_][(no)+ni_], 0, 0, 0); } \
  } while(0)

  STAGE(0, 0); STAGE(0, 1); STAGE(0, 2); STAGE(0, 3);
  STAGE(1, 0); STAGE(1, 1); STAGE(1, 2);
  asm volatile("s_waitcnt vmcnt(6)" ::: "memory");
  GSB(); GBAR();

  for (int t = 0; t < NT; ++t){
    const int p = t & 1;
    RD_A(0); RD_B(0, b0);
    if (t + 1 < NT) STAGE(t + 1, 3);
    GSB(); GBAR(); GLGKM0(); GSB();
    __builtin_amdgcn_s_setprio(1); MM(0, 0, b0); __builtin_amdgcn_s_setprio(0);
    GSB(); GBAR();
    RD_B(1, b1);
    if (t + 2 < NT) STAGE(t + 2, 0);
    GSB(); GBAR(); GLGKM0(); GSB();
    __builtin_amdgcn_s_setprio(1); MM(0, 2, b1); __builtin_amdgcn_s_setprio(0);
    GSB(); GBAR();
    RD_A(1);
    if (t + 2 < NT) STAGE(t + 2, 1);
    GSB(); GBAR(); GLGKM0(); GSB();
    __builtin_amdgcn_s_setprio(1); MM(4, 2, b1); __builtin_amdgcn_s_setprio(0);
    GSB(); GBAR();
    if (t + 2 < NT) STAGE(t + 2, 2);
    if (t < NT - 2)      { asm volatile("s_waitcnt vmcnt(6)" ::: "memory"); }
    else if (t == NT - 2){ asm volatile("s_waitcnt vmcnt(0)" ::: "memory"); }
    GSB(); GBAR(); GLGKM0(); GSB();
    __builtin_amdgcn_s_setprio(1); MM(4, 0, b0); __builtin_amdgcn_s_setprio(0);
    GSB(); GBAR();
  }

  // ---- epilogue: LDS transpose -> fully coalesced stores (2 passes of 128 rows) ----
  float* Lf = (float*)sm;
  const int ct = (tid & 63) * 4;            // thread's 4 cols (constant)
  const int rsub = tid >> 6;                // 0..7 (wave-uniform)
  f32x4 dv4;
  if (FUSE == 1) dv4 = *(const f32x4*)(Dv + bn*256 + ct);
  #pragma unroll
  for (int h = 0; h < 2; ++h){
    __syncthreads();
    #pragma unroll
    for (int q = 0; q < 4; ++q){
      const int lrow = wm*64 + q*16 + lk*4;
      #pragma unroll
      for (int ni = 0; ni < 4; ++ni){
        const int col = (ni>>1)*128 + wn*32 + (ni&1)*16 + lr;
        #pragma unroll
        for (int rr = 0; rr < 4; ++rr)
          Lf[(lrow+rr)*256 + col] = acc[h*4+q][ni][rr];
      }
    }
    __syncthreads();
    #pragma unroll
    for (int i = 0; i < 16; ++i){
      const int lrow = i*8 + rsub;
      const int grow = bm*256 + h*128 + lrow;
      f32x4 v = *(const f32x4*)(Lf + lrow*256 + ct);
      if (FUSE == 0){
        u32 lo = (u32)f2bf(v[0]) | ((u32)f2bf(v[1]) << 16);
        u32 hi = (u32)f2bf(v[2]) | ((u32)f2bf(v[3]) << 16);
        *(uint2*)(outb + (size_t)grow*NOUT + bn*256 + ct) = make_uint2(lo, hi);
      } else {
        const u32* ub = (const u32*)(Ubf + (size_t)grow*NOUT + bn*256 + ct);
        const u32 w0 = ub[0], w1 = ub[1];
        v[0] += dv4[0] * __uint_as_float(w0 << 16);
        v[1] += dv4[1] * __uint_as_float(w0 & 0xffff0000u);
        v[2] += dv4[2] * __uint_as_float(w1 << 16);
        v[3] += dv4[3] * __uint_as_float(w1 & 0xffff0000u);
        *(f32x4*)(outf + (size_t)grow*NOUT + bn*256 + ct) = v;
      }
    }
  }
#undef STAGE
#undef RD_A
#undef RD_B
#undef MM
}

// ---------------- scan phase 1: chunk-local end states ----------------
__global__ __launch_bounds__(64) void scan_p1(const u16* __restrict__ xbf, float* __restrict__ E,
                                              const float* __restrict__ th, const float* __restrict__ GL)
{
  const int g = blockIdx.x, c = blockIdx.y, l = threadIdx.x;
  const int head = g*4 + (l >> 4), p = l & 15;
  const float gamma = expf(-expf(GL[head]));
  const float theta = th[head*16 + p];
  const float cs = cosf(theta), sn = sinf(theta);
  float he = 0.f, ho = 0.f;
  const int off = g*128 + (l >> 4)*32 + p*2;
  const u16* px = xbf + (size_t)c*LCH*MD + off;
  #pragma unroll 8
  for (int t = 0; t < LCH; ++t){
    const u32 w = *(const u32*)px;
    const float xe = __uint_as_float(w << 16);
    const float xo = __uint_as_float(w & 0xffff0000u);
    const float te = fmaf(cs, he, -sn*ho);
    const float to = fmaf(sn, he,  cs*ho);
    he = fmaf(gamma, te, xe);
    ho = fmaf(gamma, to, xo);
    px += MD;
  }
  *(float2*)(E + (size_t)c*MD + off) = make_float2(he, ho);
}

// ---------------- scan phase 2: wave-parallel scan over chunks ----------------
// One block (64 lanes) per (head,pair) state; lane c owns chunks 4c..4c+3.
// Chunk transform T = gL*R(aL) is chunk-invariant -> Hillis-Steele with T^(4*2^s).
__global__ __launch_bounds__(64) void scan_p2(float* __restrict__ E,
                                              const float* __restrict__ th, const float* __restrict__ GL)
{
  const int s = blockIdx.x;                  // 0..1023
  const int head = s >> 4, p = s & 15;
  const int off = head*32 + p*2;
  const int c = threadIdx.x;
  const float gamma = expf(-expf(GL[head]));
  const float theta = th[head*16 + p];
  const float lgam = logf(gamma);
  const float gL = expf((float)LCH * lgam);
  const float aL = (float)LCH * theta;
  const float cT = cosf(aL), sT = sinf(aL);
  float2 e[4];
  #pragma unroll
  for (int j = 0; j < 4; ++j)
    e[j] = *(const float2*)(E + (size_t)(c*4 + j)*MD + off);
  // local inclusive through the lane's 4 chunks
  float2 L = e[0];
  #pragma unroll
  for (int j = 1; j < 4; ++j)
    L = make_float2(gL*(cT*L.x - sT*L.y) + e[j].x,
                    gL*(sT*L.x + cT*L.y) + e[j].y);
  // wave scan over lane-blocks, block transform T4 = gL^4 R(4aL)
  float2 G = L;
  float gs = expf(4.f*(float)LCH*lgam);
  float cw = cosf(4.f*aL), sw = sinf(4.f*aL);
  #pragma unroll
  for (int st = 0; st < 6; ++st){
    const int d = 1 << st;
    const float gx = __shfl_up(G.x, d);
    const float gy = __shfl_up(G.y, d);
    if (c >= d){
      G.x += gs*(cw*gx - sw*gy);
      G.y += gs*(sw*gx + cw*gy);
    }
    const float c2 = cw*cw - sw*sw;
    const float s2 = 2.f*cw*sw;
    gs = gs*gs; cw = c2; sw = s2;
  }
  // exclusive prefix across lanes (inclusive state through chunk 4c-1)
  const float px_ = __shfl_up(G.x, 1), py_ = __shfl_up(G.y, 1);
  float2 S = (c == 0) ? make_float2(0.f, 0.f) : make_float2(px_, py_);
  // per-chunk carries: store S (inclusive through chunk-1), advance S = T*S + e_j
  #pragma unroll
  for (int j = 0; j < 4; ++j){
    *(float2*)(E + (size_t)(c*4 + j)*MD + off) = S;
    S = make_float2(gL*(cT*S.x - sT*S.y) + e[j].x,
                    gL*(sT*S.x + cT*S.y) + e[j].y);
  }
}

// ---------------- scan phase 3: replay chunks from carry, IN-PLACE (hid == x) ----------------
__global__ __launch_bounds__(64) void scan_p3(u16* xh, const float* __restrict__ E,
                                              const float* __restrict__ th, const float* __restrict__ GL)
{
  const int g = blockIdx.x, c = blockIdx.y, l = threadIdx.x;
  const int head = g*4 + (l >> 4), p = l & 15;
  const float gamma = expf(-expf(GL[head]));
  const float theta = th[head*16 + p];
  const float cs = cosf(theta), sn = sinf(theta);
  const int off = g*128 + (l >> 4)*32 + p*2;
  const float2 cr = *(const float2*)(E + (size_t)c*MD + off);
  float he = cr.x, ho = cr.y;
  u16* px = xh + (size_t)c*LCH*MD + off;
  #pragma unroll 8
  for (int t = 0; t < LCH; ++t){
    const u32 w = *(const u32*)px;
    const float xe = __uint_as_float(w << 16);
    const float xo = __uint_as_float(w & 0xffff0000u);
    const float te = fmaf(cs, he, -sn*ho);
    const float to = fmaf(sn, he,  cs*ho);
    he = fmaf(gamma, te, xe);
    ho = fmaf(gamma, to, xo);
    *(u32*)px = (u32)f2bf(he) | ((u32)f2bf(ho) << 16);
    px += MD;
  }
}

extern "C" void kernel_launch(void* const* d_in, const int* in_sizes, int n_in,
                              void* d_out, int out_size, void* d_ws, size_t ws_size,
                              hipStream_t stream) {
  const float* U  = (const float*)d_in[0];   // (T, MD)
  const float* TH = (const float*)d_in[1];   // (H, 16)
  const float* Mm = (const float*)d_in[2];   // (H, 32, 32)
  const float* B  = (const float*)d_in[3];   // (H, 32, MD)
  const float* C  = (const float*)d_in[4];   // (MD, MD)
  const float* Dv = (const float*)d_in[5];   // (MD,)
  const float* GL = (const float*)d_in[6];   // (H, 1)
  float* Y = (float*)d_out;

  char* w = (char*)d_ws;
  u16*   u_bf = (u16*)(w);                       // 32 MB
  u16*   x_bf = (u16*)(w + 33554432);            // 32 MB
  u16*   BPw  = (u16*)(w + 67108864);            // 8 MB (dead after GEMM1)
  u16*   CPw  = (u16*)(w + 75497472);            // 8 MB
  float* Pw   = (float*)(w + 83886080);          // 256 KB
  float* part = (float*)(w + 84148224);          // 4 KB
  float* Ew   = (float*)(w + 67108864);          // 2 MB, aliases BPw (dead by scan time)

  k_prep_part<<<dim3(16, NH), 256, 0, stream>>>(B, part);
  k_expm<<<NH, dim3(32, 32), 0, stream>>>(Mm, Pw);
  k_bp<<<dim3(8, NH), 256, 0, stream>>>(B, Pw, part, GL, BPw);
  k_cp<<<dim3(8, NH), 256, 0, stream>>>(C, Pw, CPw);
  k_cvt<<<4096, 256, 0, stream>>>(U, u_bf, (T_LEN*MD)/4);

  gemm256<0><<<dim3(MD/256, T_LEN/256), 512, 0, stream>>>(
      u_bf, BPw, x_bf, nullptr, nullptr, nullptr);

  scan_p1<<<dim3(16, NCH), 64, 0, stream>>>(x_bf, Ew, TH, GL);
  scan_p2<<<1024, 64, 0, stream>>>(Ew, TH, GL);
  scan_p3<<<dim3(16, NCH), 64, 0, stream>>>(x_bf, Ew, TH, GL);

  gemm256<1><<<dim3(MD/256, T_LEN/256), 512, 0, stream>>>(
      x_bf, CPw, nullptr, Y, Dv, u_bf);
}